// Round 4
// baseline (367.830 us; speedup 1.0000x reference)
//
#include <hip/hip_runtime.h>
#include <hip/hip_bf16.h>
#include <hip/hip_fp16.h>

#define N_NODES 100000
#define N_EDGES 1600000
#define D 64
#define CHUNK 1024
#define NCHUNK ((N_NODES + CHUNK - 1) / CHUNK)   // 98

__device__ inline float hbits_to_float(unsigned bits) {
    unsigned short u = (unsigned short)bits;
    __half h;
    __builtin_memcpy(&h, &u, 2);
    return __half2float(h);
}

// ===========================================================================
// Shared build kernels
// ===========================================================================

// --- 1. histogram of row indices -------------------------------------------
__global__ void hist_kernel(const int* __restrict__ row, int* __restrict__ counts) {
    int e = blockIdx.x * blockDim.x + threadIdx.x;
    if (e >= N_EDGES) return;
    atomicAdd(&counts[row[e]], 1);
}

// --- 2a. per-chunk exclusive scan ------------------------------------------
__global__ void __launch_bounds__(256)
scan1_kernel(const int* __restrict__ counts, int* __restrict__ row_ptr,
             int* __restrict__ chunkTotals) {
    __shared__ int s[256];
    const int t = threadIdx.x;
    const int base = blockIdx.x * CHUNK + t * 4;
    int c0 = (base + 0 < N_NODES) ? counts[base + 0] : 0;
    int c1 = (base + 1 < N_NODES) ? counts[base + 1] : 0;
    int c2 = (base + 2 < N_NODES) ? counts[base + 2] : 0;
    int c3 = (base + 3 < N_NODES) ? counts[base + 3] : 0;
    const int sum = c0 + c1 + c2 + c3;
    s[t] = sum;
    __syncthreads();
    for (int off = 1; off < 256; off <<= 1) {
        int u = (t >= off) ? s[t - off] : 0;
        __syncthreads();
        s[t] += u;
        __syncthreads();
    }
    const int excl = s[t] - sum;
    if (base + 0 < N_NODES) row_ptr[base + 0] = excl;
    if (base + 1 < N_NODES) row_ptr[base + 1] = excl + c0;
    if (base + 2 < N_NODES) row_ptr[base + 2] = excl + c0 + c1;
    if (base + 3 < N_NODES) row_ptr[base + 3] = excl + c0 + c1 + c2;
    if (t == 255) chunkTotals[blockIdx.x] = s[255];
}

// --- 2b. add inter-chunk offsets; init cursor (cursor may alias counts) ----
__global__ void __launch_bounds__(256)
scan2_kernel(int* __restrict__ row_ptr, int* __restrict__ cursor,
             const int* __restrict__ chunkTotals) {
    int offset = 0;
    for (int i = 0; i < (int)blockIdx.x; ++i) offset += chunkTotals[i];
    const int idx = blockIdx.x * CHUNK + threadIdx.x * 4;
    #pragma unroll
    for (int j = 0; j < 4; ++j) {
        const int k = idx + j;
        if (k < N_NODES) {
            const int v = row_ptr[k] + offset;
            row_ptr[k] = v;
            cursor[k]  = v;
        }
    }
    if (blockIdx.x == 0 && threadIdx.x == 0) row_ptr[N_NODES] = N_EDGES;
}

// ===========================================================================
// Tier A: fp16-H + 4-byte packed edges
// ===========================================================================

// --- 0. convert H to fp16 ---------------------------------------------------
__global__ void __launch_bounds__(256)
h2half_kernel(const float* __restrict__ H, unsigned short* __restrict__ Hh) {
    const int tid = blockIdx.x * blockDim.x + threadIdx.x;   // one float4
    const int total = N_NODES * D / 4;
    if (tid >= total) return;
    const float4 f = reinterpret_cast<const float4*>(H)[tid];
    __half2 h01 = __floats2half2_rn(f.x, f.y);
    __half2 h23 = __floats2half2_rn(f.z, f.w);
    uint2 u;
    __builtin_memcpy(&u.x, &h01, 4);
    __builtin_memcpy(&u.y, &h23, 4);
    reinterpret_cast<uint2*>(Hh)[tid] = u;
}

// --- 3. scatter: pack (col<<15)|(fp16(val) low 15 bits), 4B random store ---
__global__ void scatter_pack_kernel(const int* __restrict__ row, const int* __restrict__ col,
                                    const float* __restrict__ vals,
                                    int* __restrict__ cursor,
                                    unsigned* __restrict__ pack) {
    int e = blockIdx.x * blockDim.x + threadIdx.x;
    if (e >= N_EDGES) return;
    const int pos = atomicAdd(&cursor[row[e]], 1);
    __half hv = __float2half_rn(vals[e]);          // vals >= 0 -> sign bit 0
    unsigned short hb;
    __builtin_memcpy(&hb, &hv, 2);
    pack[pos] = ((unsigned)col[e] << 15) | (hb & 0x7FFFu);
}

// --- 4. fused gather-SPMM + GCNII epilogue (fp16 gathers) ------------------
// 16 waves/block, one row per wave; lane d owns column d.
__global__ void __launch_bounds__(1024)
gather_fused_h_kernel(const int* __restrict__ row_ptr,
                      const unsigned* __restrict__ pack,
                      const unsigned short* __restrict__ Hh,
                      const float* __restrict__ H0,
                      const float* __restrict__ W,
                      const float* __restrict__ lamda_p, const float* __restrict__ alpha_p,
                      const int* __restrict__ l_p,
                      float* __restrict__ out) {
    __shared__ float Wlds[D * D];  // 16 KB
    for (int i = threadIdx.x; i < D * D; i += 1024) Wlds[i] = W[i];
    __syncthreads();

    const float alpha = alpha_p[0];
    const float beta  = logf(lamda_p[0] / (float)l_p[0] + 1.0f);

    const int wave = threadIdx.x >> 6;        // 0..15
    const int lane = threadIdx.x & 63;
    const int r = blockIdx.x * 16 + wave;
    if (r >= N_NODES) return;                 // never taken (100000 % 16 == 0 grid exact)

    const int start = row_ptr[r];
    const int end   = row_ptr[r + 1];
    const int lm    = lane & 15;

    float a0 = 0.f, a1 = 0.f, a2 = 0.f, a3 = 0.f;

    int e = start;
    for (; e + 16 <= end; e += 16) {
        const unsigned pk = pack[e + lm];     // 16-lane groups read same 64B
        #pragma unroll
        for (int k = 0; k < 16; ++k) {
            const unsigned p = (unsigned)__shfl((int)pk, k, 64);
            const int   c = (int)(p >> 15);
            const float v = hbits_to_float(p & 0x7FFFu);
            unsigned short hb = Hh[(size_t)c * D + lane];   // 128B row gather
            __half h; __builtin_memcpy(&h, &hb, 2);
            const float hf = __half2float(h);
            if ((k & 3) == 0) a0 = fmaf(v, hf, a0);
            else if ((k & 3) == 1) a1 = fmaf(v, hf, a1);
            else if ((k & 3) == 2) a2 = fmaf(v, hf, a2);
            else a3 = fmaf(v, hf, a3);
        }
    }
    const int rem = end - e;
    if (rem > 0) {
        const unsigned pk = (lm < rem) ? pack[e + lm] : 0u;
        for (int k = 0; k < rem; ++k) {
            const unsigned p = (unsigned)__shfl((int)pk, k, 64);
            const int   c = (int)(p >> 15);
            const float v = hbits_to_float(p & 0x7FFFu);
            unsigned short hb = Hh[(size_t)c * D + lane];
            __half h; __builtin_memcpy(&h, &hb, 2);
            a0 = fmaf(v, __half2float(h), a0);
        }
    }
    const float acc = (a0 + a1) + (a2 + a3);

    const long long base = (long long)r * D;
    const float sup = (1.0f - alpha) * acc + alpha * H0[base + lane];

    float dot = 0.0f;
    #pragma unroll
    for (int k = 0; k < D; ++k)
        dot = fmaf(__shfl(sup, k, 64), Wlds[k * D + lane], dot);

    out[base + lane] = (1.0f - beta) * sup + beta * dot;
}

// ===========================================================================
// Tier B (proven round-3 path): uint2 epack, f32 H
// ===========================================================================
__global__ void scatter_kernel(const int* __restrict__ row, const int* __restrict__ col,
                               const float* __restrict__ vals,
                               int* __restrict__ cursor,
                               uint2* __restrict__ epack) {
    int e = blockIdx.x * blockDim.x + threadIdx.x;
    if (e >= N_EDGES) return;
    const int pos = atomicAdd(&cursor[row[e]], 1);
    epack[pos] = make_uint2((unsigned)col[e], __float_as_uint(vals[e]));
}

__global__ void __launch_bounds__(256)
gather_fused_kernel(const int* __restrict__ row_ptr,
                    const uint2* __restrict__ epack,
                    const float* __restrict__ H, const float* __restrict__ H0,
                    const float* __restrict__ W,
                    const float* __restrict__ lamda_p, const float* __restrict__ alpha_p,
                    const int* __restrict__ l_p,
                    float* __restrict__ out) {
    __shared__ float Wlds[D * D];
    for (int i = threadIdx.x; i < D * D; i += 256) Wlds[i] = W[i];
    __syncthreads();
    const float alpha = alpha_p[0];
    const float beta  = logf(lamda_p[0] / (float)l_p[0] + 1.0f);
    const int wave = threadIdx.x >> 6;
    const int lane = threadIdx.x & 63;
    const int r = blockIdx.x * 4 + wave;
    if (r >= N_NODES) return;
    const int start = row_ptr[r];
    const int end   = row_ptr[r + 1];
    const int lm    = lane & 15;
    float a0 = 0.f, a1 = 0.f, a2 = 0.f, a3 = 0.f;
    int e = start;
    for (; e + 16 <= end; e += 16) {
        const uint2 ed = epack[e + lm];
        #pragma unroll
        for (int k = 0; k < 16; ++k) {
            const int   c = __shfl((int)ed.x, k, 64);
            const float v = __shfl(__uint_as_float(ed.y), k, 64);
            const float h = H[(size_t)c * D + lane];
            if ((k & 3) == 0) a0 = fmaf(v, h, a0);
            else if ((k & 3) == 1) a1 = fmaf(v, h, a1);
            else if ((k & 3) == 2) a2 = fmaf(v, h, a2);
            else a3 = fmaf(v, h, a3);
        }
    }
    const int rem = end - e;
    if (rem > 0) {
        const uint2 ed = (lm < rem) ? epack[e + lm] : make_uint2(0u, 0u);
        for (int k = 0; k < rem; ++k) {
            const int   c = __shfl((int)ed.x, k, 64);
            const float v = __shfl(__uint_as_float(ed.y), k, 64);
            a0 = fmaf(v, H[(size_t)c * D + lane], a0);
        }
    }
    const float acc = (a0 + a1) + (a2 + a3);
    const long long base = (long long)r * D;
    const float sup = (1.0f - alpha) * acc + alpha * H0[base + lane];
    float dot = 0.0f;
    #pragma unroll
    for (int k = 0; k < D; ++k)
        dot = fmaf(__shfl(sup, k, 64), Wlds[k * D + lane], dot);
    out[base + lane] = (1.0f - beta) * sup + beta * dot;
}

// ===========================================================================
// Tier C fallback: f32 atomic scatter + separate epilogue
// ===========================================================================
__global__ void spmm_atomic_kernel(const int* __restrict__ row,
                                   const int* __restrict__ col,
                                   const float* __restrict__ vals,
                                   const float* __restrict__ H,
                                   float* __restrict__ AH) {
    const long long total = (long long)N_EDGES * 16;
    long long idx = (long long)blockIdx.x * blockDim.x + threadIdx.x;
    if (idx >= total) return;
    const int e   = (int)(idx >> 4);
    const int sub = (int)(idx & 15);
    const int r   = row[e];
    const int c   = col[e];
    const float v = vals[e];
    const float4 h = *reinterpret_cast<const float4*>(&H[(long long)c * D + sub * 4]);
    float* dst = &AH[(long long)r * D + sub * 4];
    atomicAdd(dst + 0, v * h.x);
    atomicAdd(dst + 1, v * h.y);
    atomicAdd(dst + 2, v * h.z);
    atomicAdd(dst + 3, v * h.w);
}

__global__ void __launch_bounds__(256)
gcnii_epilogue_kernel(float* __restrict__ AH_out,
                      const float* __restrict__ H0,
                      const float* __restrict__ W,
                      const float* __restrict__ lamda_p,
                      const float* __restrict__ alpha_p,
                      const int* __restrict__ l_p) {
    __shared__ float Wlds[D * D];
    for (int i = threadIdx.x; i < D * D; i += 256) Wlds[i] = W[i];
    __syncthreads();
    const float alpha = alpha_p[0];
    const float beta  = logf(lamda_p[0] / (float)l_p[0] + 1.0f);
    const int wave = threadIdx.x >> 6;
    const int lane = threadIdx.x & 63;
    const int r = blockIdx.x * 4 + wave;
    if (r >= N_NODES) return;
    const long long base = (long long)r * D;
    const float sup = (1.0f - alpha) * AH_out[base + lane] + alpha * H0[base + lane];
    float acc = 0.0f;
    #pragma unroll
    for (int k = 0; k < D; ++k)
        acc = fmaf(__shfl(sup, k, 64), Wlds[k * D + lane], acc);
    AH_out[base + lane] = (1.0f - beta) * sup + beta * acc;
}

// ===========================================================================
extern "C" void kernel_launch(void* const* d_in, const int* in_sizes, int n_in,
                              void* d_out, int out_size, void* d_ws, size_t ws_size,
                              hipStream_t stream) {
    const int*   row   = (const int*)  d_in[0];
    const int*   col   = (const int*)  d_in[1];
    const float* vals  = (const float*)d_in[2];
    const float* H     = (const float*)d_in[3];
    const float* H0    = (const float*)d_in[4];
    const float* W     = (const float*)d_in[5];
    const float* lamda = (const float*)d_in[6];
    const float* alpha = (const float*)d_in[7];
    const int*   l     = (const int*)  d_in[8];
    float* out = (float*)d_out;

    // Tier A layout (4B words):
    //   counts/cursor : [0, 100000)
    //   row_ptr       : [100000, 200001)  (pad to 200064)
    //   totals        : [200064, 200192)
    //   pack          : [200192, 1800192)
    //   Hh (fp16)     : [1800192, 5000192)
    const size_t neededA = (size_t)5000192 * 4;
    // Tier B layout: as round-3 (3500192 words)
    const size_t neededB = (size_t)3500192 * 4;

    if (ws_size >= neededA) {
        int*            counts  = (int*)d_ws;          // doubles as cursor
        int*            row_ptr = counts + 100000;
        int*            totals  = counts + 200064;
        unsigned*       pack    = (unsigned*)(counts + 200192);
        unsigned short* Hh      = (unsigned short*)(counts + 1800192);

        h2half_kernel<<<(N_NODES * D / 4 + 255) / 256, 256, 0, stream>>>(H, Hh);
        hipMemsetAsync(counts, 0, (size_t)N_NODES * sizeof(int), stream);
        hist_kernel<<<(N_EDGES + 255) / 256, 256, 0, stream>>>(row, counts);
        scan1_kernel<<<NCHUNK, 256, 0, stream>>>(counts, row_ptr, totals);
        scan2_kernel<<<NCHUNK, 256, 0, stream>>>(row_ptr, counts, totals);
        scatter_pack_kernel<<<(N_EDGES + 255) / 256, 256, 0, stream>>>(row, col, vals,
                                                                       counts, pack);
        gather_fused_h_kernel<<<(N_NODES + 15) / 16, 1024, 0, stream>>>(
            row_ptr, pack, Hh, H0, W, lamda, alpha, l, out);
    } else if (ws_size >= neededB) {
        int*   counts  = (int*)d_ws;
        int*   row_ptr = counts + 100000;
        int*   cursor  = counts + 200064;
        int*   totals  = counts + 300064;
        uint2* epack   = (uint2*)(counts + 300192);

        hipMemsetAsync(counts, 0, (size_t)N_NODES * sizeof(int), stream);
        hist_kernel<<<(N_EDGES + 255) / 256, 256, 0, stream>>>(row, counts);
        scan1_kernel<<<NCHUNK, 256, 0, stream>>>(counts, row_ptr, totals);
        scan2_kernel<<<NCHUNK, 256, 0, stream>>>(row_ptr, cursor, totals);
        scatter_kernel<<<(N_EDGES + 255) / 256, 256, 0, stream>>>(row, col, vals,
                                                                  cursor, epack);
        gather_fused_kernel<<<(N_NODES + 3) / 4, 256, 0, stream>>>(
            row_ptr, epack, H, H0, W, lamda, alpha, l, out);
    } else {
        hipMemsetAsync(out, 0, (size_t)out_size * sizeof(float), stream);
        const long long total = (long long)N_EDGES * 16;
        spmm_atomic_kernel<<<(int)((total + 255) / 256), 256, 0, stream>>>(row, col, vals, H, out);
        gcnii_epilogue_kernel<<<(N_NODES + 3) / 4, 256, 0, stream>>>(out, H0, W,
                                                                     lamda, alpha, l);
    }
}

// Round 5
// 338.447 us; speedup vs baseline: 1.0868x; 1.0868x over previous
//
#include <hip/hip_runtime.h>
#include <hip/hip_bf16.h>
#include <hip/hip_fp16.h>

#define N_NODES 100000
#define N_EDGES 1600000
#define D 64
#define CHUNK 1024
#define NCHUNK ((N_NODES + CHUNK - 1) / CHUNK)   // 98

// ===========================================================================
// Shared build kernels
// ===========================================================================

__global__ void hist_kernel(const int* __restrict__ row, int* __restrict__ counts) {
    int e = blockIdx.x * blockDim.x + threadIdx.x;
    if (e >= N_EDGES) return;
    atomicAdd(&counts[row[e]], 1);
}

__global__ void __launch_bounds__(256)
scan1_kernel(const int* __restrict__ counts, int* __restrict__ row_ptr,
             int* __restrict__ chunkTotals) {
    __shared__ int s[256];
    const int t = threadIdx.x;
    const int base = blockIdx.x * CHUNK + t * 4;
    int c0 = (base + 0 < N_NODES) ? counts[base + 0] : 0;
    int c1 = (base + 1 < N_NODES) ? counts[base + 1] : 0;
    int c2 = (base + 2 < N_NODES) ? counts[base + 2] : 0;
    int c3 = (base + 3 < N_NODES) ? counts[base + 3] : 0;
    const int sum = c0 + c1 + c2 + c3;
    s[t] = sum;
    __syncthreads();
    for (int off = 1; off < 256; off <<= 1) {
        int u = (t >= off) ? s[t - off] : 0;
        __syncthreads();
        s[t] += u;
        __syncthreads();
    }
    const int excl = s[t] - sum;
    if (base + 0 < N_NODES) row_ptr[base + 0] = excl;
    if (base + 1 < N_NODES) row_ptr[base + 1] = excl + c0;
    if (base + 2 < N_NODES) row_ptr[base + 2] = excl + c0 + c1;
    if (base + 3 < N_NODES) row_ptr[base + 3] = excl + c0 + c1 + c2;
    if (t == 255) chunkTotals[blockIdx.x] = s[255];
}

__global__ void __launch_bounds__(256)
scan2_kernel(int* __restrict__ row_ptr, int* __restrict__ cursor,
             const int* __restrict__ chunkTotals) {
    int offset = 0;
    for (int i = 0; i < (int)blockIdx.x; ++i) offset += chunkTotals[i];
    const int idx = blockIdx.x * CHUNK + threadIdx.x * 4;
    #pragma unroll
    for (int j = 0; j < 4; ++j) {
        const int k = idx + j;
        if (k < N_NODES) {
            const int v = row_ptr[k] + offset;
            row_ptr[k] = v;
            cursor[k]  = v;
        }
    }
    if (blockIdx.x == 0 && threadIdx.x == 0) row_ptr[N_NODES] = N_EDGES;
}

// ===========================================================================
// Tier A: fp16-H, 4-byte packed edges, scalar-load gather + LDS mini-GEMM
// ===========================================================================

__global__ void __launch_bounds__(256)
h2half_kernel(const float* __restrict__ H, unsigned short* __restrict__ Hh) {
    const int tid = blockIdx.x * blockDim.x + threadIdx.x;
    const int total = N_NODES * D / 4;
    if (tid >= total) return;
    const float4 f = reinterpret_cast<const float4*>(H)[tid];
    __half2 h01 = __floats2half2_rn(f.x, f.y);
    __half2 h23 = __floats2half2_rn(f.z, f.w);
    uint2 u;
    __builtin_memcpy(&u.x, &h01, 4);
    __builtin_memcpy(&u.y, &h23, 4);
    reinterpret_cast<uint2*>(Hh)[tid] = u;
}

__global__ void scatter_pack_kernel(const int* __restrict__ row, const int* __restrict__ col,
                                    const float* __restrict__ vals,
                                    int* __restrict__ cursor,
                                    unsigned* __restrict__ pack) {
    int e = blockIdx.x * blockDim.x + threadIdx.x;
    if (e >= N_EDGES) return;
    const int pos = atomicAdd(&cursor[row[e]], 1);
    __half hv = __float2half_rn(vals[e]);          // vals >= 0 -> sign bit 0
    unsigned short hb;
    __builtin_memcpy(&hb, &hv, 2);
    pack[pos] = ((unsigned)col[e] << 15) | (hb & 0x7FFFu);
}

// one block = 64 rows. Phase 1: 4 waves gather 16 rows each (scalar edge
// loads, no shuffles), writing support rows to LDS supT[d][r].
// Phase 2: 64x64 @ 64x64 mini-GEMM, 4x4 register tile per thread,
// 2 x ds_read_b128 per k. Zero ds_bpermute anywhere.
__global__ void __launch_bounds__(256)
gather_gemm_kernel(const int* __restrict__ row_ptr,
                   const unsigned* __restrict__ pack,
                   const unsigned short* __restrict__ Hh,
                   const float* __restrict__ H0,
                   const float* __restrict__ W,
                   const float* __restrict__ lamda_p, const float* __restrict__ alpha_p,
                   const int* __restrict__ l_p,
                   float* __restrict__ out) {
    __shared__ float supT[D][68];   // supT[d][local_r]; stride 68 keeps 16B align
    __shared__ float Wl[D][D];      // W as-is

    const int tid = threadIdx.x;
    for (int i = tid; i < D * D; i += 256) ((float*)Wl)[i] = W[i];

    const float alpha = alpha_p[0];
    const float beta  = logf(lamda_p[0] / (float)l_p[0] + 1.0f);

    const int wave = tid >> 6;
    const int lane = tid & 63;
    const int R0 = blockIdx.x * 64;

    // ---------------- phase 1: gather ----------------
    for (int i = 0; i < 16; ++i) {
        const int r = R0 + wave * 16 + i;
        if (r < N_NODES) {
            const int s = __builtin_amdgcn_readfirstlane(row_ptr[r]);
            const int t = __builtin_amdgcn_readfirstlane(row_ptr[r + 1]);
            float a0 = 0.f, a1 = 0.f, a2 = 0.f, a3 = 0.f;
            int e = s;
            for (; e + 16 <= t; e += 16) {
                #pragma unroll
                for (int k = 0; k < 16; ++k) {
                    const unsigned p = pack[e + k];          // scalar (uniform) load
                    const int c = (int)(p >> 15);
                    unsigned short us = (unsigned short)(p & 0x7FFFu);
                    __half hv; __builtin_memcpy(&hv, &us, 2);
                    const float v = __half2float(hv);
                    unsigned short hb = Hh[(size_t)c * D + lane];
                    __half hh; __builtin_memcpy(&hh, &hb, 2);
                    const float hf = __half2float(hh);
                    if ((k & 3) == 0) a0 = fmaf(v, hf, a0);
                    else if ((k & 3) == 1) a1 = fmaf(v, hf, a1);
                    else if ((k & 3) == 2) a2 = fmaf(v, hf, a2);
                    else a3 = fmaf(v, hf, a3);
                }
            }
            #pragma unroll
            for (int k = 0; k < 16; ++k) {                   // uniform-branch tail
                if (e + k < t) {
                    const unsigned p = pack[e + k];
                    const int c = (int)(p >> 15);
                    unsigned short us = (unsigned short)(p & 0x7FFFu);
                    __half hv; __builtin_memcpy(&hv, &us, 2);
                    const float v = __half2float(hv);
                    unsigned short hb = Hh[(size_t)c * D + lane];
                    __half hh; __builtin_memcpy(&hh, &hb, 2);
                    a0 = fmaf(v, __half2float(hh), a0);
                }
            }
            const float acc = (a0 + a1) + (a2 + a3);
            const float sup = (1.0f - alpha) * acc + alpha * H0[(size_t)r * D + lane];
            supT[lane][wave * 16 + i] = sup;
        }
    }
    __syncthreads();

    // ---------------- phase 2: 64x64 mini-GEMM ----------------
    const int ty = tid >> 4;     // 0..15 -> rows 4*ty..4*ty+3
    const int tx = tid & 15;     // 0..15 -> cols 4*tx..4*tx+3
    float acc[4][4] = {{0.f}};

    #pragma unroll 8
    for (int k = 0; k < D; ++k) {
        const float4 A = *reinterpret_cast<const float4*>(&supT[k][4 * ty]);
        const float4 B = *reinterpret_cast<const float4*>(&Wl[k][4 * tx]);
        acc[0][0] = fmaf(A.x, B.x, acc[0][0]); acc[0][1] = fmaf(A.x, B.y, acc[0][1]);
        acc[0][2] = fmaf(A.x, B.z, acc[0][2]); acc[0][3] = fmaf(A.x, B.w, acc[0][3]);
        acc[1][0] = fmaf(A.y, B.x, acc[1][0]); acc[1][1] = fmaf(A.y, B.y, acc[1][1]);
        acc[1][2] = fmaf(A.y, B.z, acc[1][2]); acc[1][3] = fmaf(A.y, B.w, acc[1][3]);
        acc[2][0] = fmaf(A.z, B.x, acc[2][0]); acc[2][1] = fmaf(A.z, B.y, acc[2][1]);
        acc[2][2] = fmaf(A.z, B.z, acc[2][2]); acc[2][3] = fmaf(A.z, B.w, acc[2][3]);
        acc[3][0] = fmaf(A.w, B.x, acc[3][0]); acc[3][1] = fmaf(A.w, B.y, acc[3][1]);
        acc[3][2] = fmaf(A.w, B.z, acc[3][2]); acc[3][3] = fmaf(A.w, B.w, acc[3][3]);
    }

    #pragma unroll
    for (int i = 0; i < 4; ++i) {
        const int r = R0 + 4 * ty + i;
        if (r < N_NODES) {
            float4 o;
            o.x = (1.0f - beta) * supT[4 * tx + 0][4 * ty + i] + beta * acc[i][0];
            o.y = (1.0f - beta) * supT[4 * tx + 1][4 * ty + i] + beta * acc[i][1];
            o.z = (1.0f - beta) * supT[4 * tx + 2][4 * ty + i] + beta * acc[i][2];
            o.w = (1.0f - beta) * supT[4 * tx + 3][4 * ty + i] + beta * acc[i][3];
            *reinterpret_cast<float4*>(&out[(size_t)r * D + 4 * tx]) = o;
        }
    }
}

// ===========================================================================
// Tier B (round-3 proven): uint2 epack, f32 H, shuffle path
// ===========================================================================
__global__ void scatter_kernel(const int* __restrict__ row, const int* __restrict__ col,
                               const float* __restrict__ vals,
                               int* __restrict__ cursor,
                               uint2* __restrict__ epack) {
    int e = blockIdx.x * blockDim.x + threadIdx.x;
    if (e >= N_EDGES) return;
    const int pos = atomicAdd(&cursor[row[e]], 1);
    epack[pos] = make_uint2((unsigned)col[e], __float_as_uint(vals[e]));
}

__global__ void __launch_bounds__(256)
gather_fused_kernel(const int* __restrict__ row_ptr,
                    const uint2* __restrict__ epack,
                    const float* __restrict__ H, const float* __restrict__ H0,
                    const float* __restrict__ W,
                    const float* __restrict__ lamda_p, const float* __restrict__ alpha_p,
                    const int* __restrict__ l_p,
                    float* __restrict__ out) {
    __shared__ float Wlds[D * D];
    for (int i = threadIdx.x; i < D * D; i += 256) Wlds[i] = W[i];
    __syncthreads();
    const float alpha = alpha_p[0];
    const float beta  = logf(lamda_p[0] / (float)l_p[0] + 1.0f);
    const int wave = threadIdx.x >> 6;
    const int lane = threadIdx.x & 63;
    const int r = blockIdx.x * 4 + wave;
    if (r >= N_NODES) return;
    const int start = row_ptr[r];
    const int end   = row_ptr[r + 1];
    const int lm    = lane & 15;
    float a0 = 0.f, a1 = 0.f, a2 = 0.f, a3 = 0.f;
    int e = start;
    for (; e + 16 <= end; e += 16) {
        const uint2 ed = epack[e + lm];
        #pragma unroll
        for (int k = 0; k < 16; ++k) {
            const int   c = __shfl((int)ed.x, k, 64);
            const float v = __shfl(__uint_as_float(ed.y), k, 64);
            const float h = H[(size_t)c * D + lane];
            if ((k & 3) == 0) a0 = fmaf(v, h, a0);
            else if ((k & 3) == 1) a1 = fmaf(v, h, a1);
            else if ((k & 3) == 2) a2 = fmaf(v, h, a2);
            else a3 = fmaf(v, h, a3);
        }
    }
    const int rem = end - e;
    if (rem > 0) {
        const uint2 ed = (lm < rem) ? epack[e + lm] : make_uint2(0u, 0u);
        for (int k = 0; k < rem; ++k) {
            const int   c = __shfl((int)ed.x, k, 64);
            const float v = __shfl(__uint_as_float(ed.y), k, 64);
            a0 = fmaf(v, H[(size_t)c * D + lane], a0);
        }
    }
    const float acc = (a0 + a1) + (a2 + a3);
    const long long base = (long long)r * D;
    const float sup = (1.0f - alpha) * acc + alpha * H0[base + lane];
    float dot = 0.0f;
    #pragma unroll
    for (int k = 0; k < D; ++k)
        dot = fmaf(__shfl(sup, k, 64), Wlds[k * D + lane], dot);
    out[base + lane] = (1.0f - beta) * sup + beta * dot;
}

// ===========================================================================
// Tier C fallback: f32 atomic scatter + separate epilogue
// ===========================================================================
__global__ void spmm_atomic_kernel(const int* __restrict__ row,
                                   const int* __restrict__ col,
                                   const float* __restrict__ vals,
                                   const float* __restrict__ H,
                                   float* __restrict__ AH) {
    const long long total = (long long)N_EDGES * 16;
    long long idx = (long long)blockIdx.x * blockDim.x + threadIdx.x;
    if (idx >= total) return;
    const int e   = (int)(idx >> 4);
    const int sub = (int)(idx & 15);
    const int r   = row[e];
    const int c   = col[e];
    const float v = vals[e];
    const float4 h = *reinterpret_cast<const float4*>(&H[(long long)c * D + sub * 4]);
    float* dst = &AH[(long long)r * D + sub * 4];
    atomicAdd(dst + 0, v * h.x);
    atomicAdd(dst + 1, v * h.y);
    atomicAdd(dst + 2, v * h.z);
    atomicAdd(dst + 3, v * h.w);
}

__global__ void __launch_bounds__(256)
gcnii_epilogue_kernel(float* __restrict__ AH_out,
                      const float* __restrict__ H0,
                      const float* __restrict__ W,
                      const float* __restrict__ lamda_p,
                      const float* __restrict__ alpha_p,
                      const int* __restrict__ l_p) {
    __shared__ float Wlds[D * D];
    for (int i = threadIdx.x; i < D * D; i += 256) Wlds[i] = W[i];
    __syncthreads();
    const float alpha = alpha_p[0];
    const float beta  = logf(lamda_p[0] / (float)l_p[0] + 1.0f);
    const int wave = threadIdx.x >> 6;
    const int lane = threadIdx.x & 63;
    const int r = blockIdx.x * 4 + wave;
    if (r >= N_NODES) return;
    const long long base = (long long)r * D;
    const float sup = (1.0f - alpha) * AH_out[base + lane] + alpha * H0[base + lane];
    float acc = 0.0f;
    #pragma unroll
    for (int k = 0; k < D; ++k)
        acc = fmaf(__shfl(sup, k, 64), Wlds[k * D + lane], acc);
    AH_out[base + lane] = (1.0f - beta) * sup + beta * acc;
}

// ===========================================================================
extern "C" void kernel_launch(void* const* d_in, const int* in_sizes, int n_in,
                              void* d_out, int out_size, void* d_ws, size_t ws_size,
                              hipStream_t stream) {
    const int*   row   = (const int*)  d_in[0];
    const int*   col   = (const int*)  d_in[1];
    const float* vals  = (const float*)d_in[2];
    const float* H     = (const float*)d_in[3];
    const float* H0    = (const float*)d_in[4];
    const float* W     = (const float*)d_in[5];
    const float* lamda = (const float*)d_in[6];
    const float* alpha = (const float*)d_in[7];
    const int*   l     = (const int*)  d_in[8];
    float* out = (float*)d_out;

    // Tier A layout (4B words):
    //   counts/cursor : [0, 100000)
    //   row_ptr       : [100000, 200001)  (pad to 200064)
    //   totals        : [200064, 200192)
    //   pack          : [200192, 1800256)   (1.6M + 64 pad for tail s_loads)
    //   Hh (fp16)     : [1800256, 5000256)
    const size_t neededA = (size_t)5000256 * 4;
    const size_t neededB = (size_t)3500192 * 4;

    if (ws_size >= neededA) {
        int*            counts  = (int*)d_ws;          // doubles as cursor
        int*            row_ptr = counts + 100000;
        int*            totals  = counts + 200064;
        unsigned*       pack    = (unsigned*)(counts + 200192);
        unsigned short* Hh      = (unsigned short*)(counts + 1800256);

        h2half_kernel<<<(N_NODES * D / 4 + 255) / 256, 256, 0, stream>>>(H, Hh);
        hipMemsetAsync(counts, 0, (size_t)N_NODES * sizeof(int), stream);
        hist_kernel<<<(N_EDGES + 255) / 256, 256, 0, stream>>>(row, counts);
        scan1_kernel<<<NCHUNK, 256, 0, stream>>>(counts, row_ptr, totals);
        scan2_kernel<<<NCHUNK, 256, 0, stream>>>(row_ptr, counts, totals);
        scatter_pack_kernel<<<(N_EDGES + 255) / 256, 256, 0, stream>>>(row, col, vals,
                                                                       counts, pack);
        gather_gemm_kernel<<<(N_NODES + 63) / 64, 256, 0, stream>>>(
            row_ptr, pack, Hh, H0, W, lamda, alpha, l, out);
    } else if (ws_size >= neededB) {
        int*   counts  = (int*)d_ws;
        int*   row_ptr = counts + 100000;
        int*   cursor  = counts + 200064;
        int*   totals  = counts + 300064;
        uint2* epack   = (uint2*)(counts + 300192);

        hipMemsetAsync(counts, 0, (size_t)N_NODES * sizeof(int), stream);
        hist_kernel<<<(N_EDGES + 255) / 256, 256, 0, stream>>>(row, counts);
        scan1_kernel<<<NCHUNK, 256, 0, stream>>>(counts, row_ptr, totals);
        scan2_kernel<<<NCHUNK, 256, 0, stream>>>(row_ptr, cursor, totals);
        scatter_kernel<<<(N_EDGES + 255) / 256, 256, 0, stream>>>(row, col, vals,
                                                                  cursor, epack);
        gather_fused_kernel<<<(N_NODES + 3) / 4, 256, 0, stream>>>(
            row_ptr, epack, H, H0, W, lamda, alpha, l, out);
    } else {
        hipMemsetAsync(out, 0, (size_t)out_size * sizeof(float), stream);
        const long long total = (long long)N_EDGES * 16;
        spmm_atomic_kernel<<<(int)((total + 255) / 256), 256, 0, stream>>>(row, col, vals, H, out);
        gcnii_epilogue_kernel<<<(N_NODES + 3) / 4, 256, 0, stream>>>(out, H0, W,
                                                                     lamda, alpha, l);
    }
}

// Round 6
// 276.428 us; speedup vs baseline: 1.3307x; 1.2244x over previous
//
#include <hip/hip_runtime.h>
#include <hip/hip_bf16.h>
#include <hip/hip_fp16.h>

#define N_NODES 100000
#define N_EDGES 1600000
#define D 64
#define CHUNK 1024
#define NCHUNK ((N_NODES + CHUNK - 1) / CHUNK)   // 98

// ===========================================================================
// Shared build kernels
// ===========================================================================

__global__ void hist_kernel(const int* __restrict__ row, int* __restrict__ counts) {
    int e = blockIdx.x * blockDim.x + threadIdx.x;
    if (e >= N_EDGES) return;
    atomicAdd(&counts[row[e]], 1);
}

__global__ void __launch_bounds__(256)
scan1_kernel(const int* __restrict__ counts, int* __restrict__ row_ptr,
             int* __restrict__ chunkTotals) {
    __shared__ int s[256];
    const int t = threadIdx.x;
    const int base = blockIdx.x * CHUNK + t * 4;
    int c0 = (base + 0 < N_NODES) ? counts[base + 0] : 0;
    int c1 = (base + 1 < N_NODES) ? counts[base + 1] : 0;
    int c2 = (base + 2 < N_NODES) ? counts[base + 2] : 0;
    int c3 = (base + 3 < N_NODES) ? counts[base + 3] : 0;
    const int sum = c0 + c1 + c2 + c3;
    s[t] = sum;
    __syncthreads();
    for (int off = 1; off < 256; off <<= 1) {
        int u = (t >= off) ? s[t - off] : 0;
        __syncthreads();
        s[t] += u;
        __syncthreads();
    }
    const int excl = s[t] - sum;
    if (base + 0 < N_NODES) row_ptr[base + 0] = excl;
    if (base + 1 < N_NODES) row_ptr[base + 1] = excl + c0;
    if (base + 2 < N_NODES) row_ptr[base + 2] = excl + c0 + c1;
    if (base + 3 < N_NODES) row_ptr[base + 3] = excl + c0 + c1 + c2;
    if (t == 255) chunkTotals[blockIdx.x] = s[255];
}

__global__ void __launch_bounds__(256)
scan2_kernel(int* __restrict__ row_ptr, int* __restrict__ cursor,
             const int* __restrict__ chunkTotals) {
    int offset = 0;
    for (int i = 0; i < (int)blockIdx.x; ++i) offset += chunkTotals[i];
    const int idx = blockIdx.x * CHUNK + threadIdx.x * 4;
    #pragma unroll
    for (int j = 0; j < 4; ++j) {
        const int k = idx + j;
        if (k < N_NODES) {
            const int v = row_ptr[k] + offset;
            row_ptr[k] = v;
            cursor[k]  = v;
        }
    }
    if (blockIdx.x == 0 && threadIdx.x == 0) row_ptr[N_NODES] = N_EDGES;
}

// ===========================================================================
// Tier A: fp16-H, 4-byte packed edges, branch-free batched gather + LDS GEMM
// ===========================================================================

__global__ void __launch_bounds__(256)
h2half_kernel(const float* __restrict__ H, unsigned short* __restrict__ Hh) {
    const int tid = blockIdx.x * blockDim.x + threadIdx.x;
    const int total = N_NODES * D / 4;
    if (tid >= total) return;
    const float4 f = reinterpret_cast<const float4*>(H)[tid];
    __half2 h01 = __floats2half2_rn(f.x, f.y);
    __half2 h23 = __floats2half2_rn(f.z, f.w);
    uint2 u;
    __builtin_memcpy(&u.x, &h01, 4);
    __builtin_memcpy(&u.y, &h23, 4);
    reinterpret_cast<uint2*>(Hh)[tid] = u;
}

__global__ void scatter_pack_kernel(const int* __restrict__ row, const int* __restrict__ col,
                                    const float* __restrict__ vals,
                                    int* __restrict__ cursor,
                                    unsigned* __restrict__ pack) {
    int e = blockIdx.x * blockDim.x + threadIdx.x;
    if (e >= N_EDGES) return;
    const int pos = atomicAdd(&cursor[row[e]], 1);
    __half hv = __float2half_rn(vals[e]);          // vals >= 0 -> sign bit 0
    unsigned short hb;
    __builtin_memcpy(&hb, &hv, 2);
    pack[pos] = ((unsigned)col[e] << 15) | (hb & 0x7FFFu);
}

__device__ inline float h_from_bits(unsigned bits) {
    unsigned short us = (unsigned short)bits;
    __half h;
    __builtin_memcpy(&h, &us, 2);
    return __half2float(h);
}

// one block = 64 rows. Phase 1: 4 waves gather 16 rows each. Per 16-edge
// group: lanes 0..15 load packed edges (one coalesced VMEM), readlane (VALU)
// broadcasts to SGPR, 16 independent ushort gathers batch. Tail handled by
// clamping the edge index (dummy gathers hit cache; v selected to 0).
// Phase 2: 64x64 @ 64x64 mini-GEMM, 4x4 register tile per thread.
__global__ void __launch_bounds__(256)
gather_gemm_kernel(const int* __restrict__ row_ptr,
                   const unsigned* __restrict__ pack,
                   const unsigned short* __restrict__ Hh,
                   const float* __restrict__ H0,
                   const float* __restrict__ W,
                   const float* __restrict__ lamda_p, const float* __restrict__ alpha_p,
                   const int* __restrict__ l_p,
                   float* __restrict__ out) {
    __shared__ float supT[D][68];   // supT[d][local_r]
    __shared__ float Wl[D][D];

    const int tid = threadIdx.x;
    for (int i = tid; i < D * D; i += 256) ((float*)Wl)[i] = W[i];

    const float alpha = alpha_p[0];
    const float beta  = logf(lamda_p[0] / (float)l_p[0] + 1.0f);

    const int wave = tid >> 6;
    const int lane = tid & 63;
    const int R0 = blockIdx.x * 64;
    const int rbase = R0 + wave * 16;

    // lane-parallel row_ptr fetch: lanes 0..16 hold bounds for this wave's rows
    int rpidx = rbase + ((lane < 17) ? lane : 16);
    if (rpidx > N_NODES) rpidx = N_NODES;
    const int rp_l = row_ptr[rpidx];

    // ---------------- phase 1: gather ----------------
    for (int i = 0; i < 16; ++i) {
        const int r = rbase + i;
        if (r >= N_NODES) break;                       // uniform
        const int s = __builtin_amdgcn_readlane(rp_l, i);
        const int t = __builtin_amdgcn_readlane(rp_l, i + 1);

        float a0 = 0.f, a1 = 0.f, a2 = 0.f, a3 = 0.f;
        for (int e = s; e < t; e += 16) {
            int ei = e + (lane & 15);
            if (ei > t - 1) ei = t - 1;                // clamp (t > s >= 0 here)
            const unsigned p_l = pack[ei];             // one coalesced load / group
            #pragma unroll
            for (int k = 0; k < 16; ++k) {
                const unsigned p = (unsigned)__builtin_amdgcn_readlane((int)p_l, k);
                const unsigned vbits = (e + k < t) ? (p & 0x7FFFu) : 0u;  // scalar sel
                const float v = h_from_bits(vbits);
                const unsigned short hb = Hh[(size_t)(p >> 15) * D + lane];
                __half hh; __builtin_memcpy(&hh, &hb, 2);
                const float hf = __half2float(hh);
                if ((k & 3) == 0) a0 = fmaf(v, hf, a0);
                else if ((k & 3) == 1) a1 = fmaf(v, hf, a1);
                else if ((k & 3) == 2) a2 = fmaf(v, hf, a2);
                else a3 = fmaf(v, hf, a3);
            }
        }
        const float acc = (a0 + a1) + (a2 + a3);
        const float sup = (1.0f - alpha) * acc + alpha * H0[(size_t)r * D + lane];
        supT[lane][wave * 16 + i] = sup;
    }
    __syncthreads();

    // ---------------- phase 2: 64x64 mini-GEMM ----------------
    const int ty = tid >> 4;     // 0..15 -> rows 4*ty..4*ty+3
    const int tx = tid & 15;     // 0..15 -> cols 4*tx..4*tx+3
    float acc[4][4] = {{0.f}};

    #pragma unroll 8
    for (int k = 0; k < D; ++k) {
        const float4 A = *reinterpret_cast<const float4*>(&supT[k][4 * ty]);
        const float4 B = *reinterpret_cast<const float4*>(&Wl[k][4 * tx]);
        acc[0][0] = fmaf(A.x, B.x, acc[0][0]); acc[0][1] = fmaf(A.x, B.y, acc[0][1]);
        acc[0][2] = fmaf(A.x, B.z, acc[0][2]); acc[0][3] = fmaf(A.x, B.w, acc[0][3]);
        acc[1][0] = fmaf(A.y, B.x, acc[1][0]); acc[1][1] = fmaf(A.y, B.y, acc[1][1]);
        acc[1][2] = fmaf(A.y, B.z, acc[1][2]); acc[1][3] = fmaf(A.y, B.w, acc[1][3]);
        acc[2][0] = fmaf(A.z, B.x, acc[2][0]); acc[2][1] = fmaf(A.z, B.y, acc[2][1]);
        acc[2][2] = fmaf(A.z, B.z, acc[2][2]); acc[2][3] = fmaf(A.z, B.w, acc[2][3]);
        acc[3][0] = fmaf(A.w, B.x, acc[3][0]); acc[3][1] = fmaf(A.w, B.y, acc[3][1]);
        acc[3][2] = fmaf(A.w, B.z, acc[3][2]); acc[3][3] = fmaf(A.w, B.w, acc[3][3]);
    }

    #pragma unroll
    for (int i = 0; i < 4; ++i) {
        const int r = R0 + 4 * ty + i;
        if (r < N_NODES) {
            float4 o;
            o.x = (1.0f - beta) * supT[4 * tx + 0][4 * ty + i] + beta * acc[i][0];
            o.y = (1.0f - beta) * supT[4 * tx + 1][4 * ty + i] + beta * acc[i][1];
            o.z = (1.0f - beta) * supT[4 * tx + 2][4 * ty + i] + beta * acc[i][2];
            o.w = (1.0f - beta) * supT[4 * tx + 3][4 * ty + i] + beta * acc[i][3];
            *reinterpret_cast<float4*>(&out[(size_t)r * D + 4 * tx]) = o;
        }
    }
}

// ===========================================================================
// Tier B (round-3 proven): uint2 epack, f32 H, shuffle path
// ===========================================================================
__global__ void scatter_kernel(const int* __restrict__ row, const int* __restrict__ col,
                               const float* __restrict__ vals,
                               int* __restrict__ cursor,
                               uint2* __restrict__ epack) {
    int e = blockIdx.x * blockDim.x + threadIdx.x;
    if (e >= N_EDGES) return;
    const int pos = atomicAdd(&cursor[row[e]], 1);
    epack[pos] = make_uint2((unsigned)col[e], __float_as_uint(vals[e]));
}

__global__ void __launch_bounds__(256)
gather_fused_kernel(const int* __restrict__ row_ptr,
                    const uint2* __restrict__ epack,
                    const float* __restrict__ H, const float* __restrict__ H0,
                    const float* __restrict__ W,
                    const float* __restrict__ lamda_p, const float* __restrict__ alpha_p,
                    const int* __restrict__ l_p,
                    float* __restrict__ out) {
    __shared__ float Wlds[D * D];
    for (int i = threadIdx.x; i < D * D; i += 256) Wlds[i] = W[i];
    __syncthreads();
    const float alpha = alpha_p[0];
    const float beta  = logf(lamda_p[0] / (float)l_p[0] + 1.0f);
    const int wave = threadIdx.x >> 6;
    const int lane = threadIdx.x & 63;
    const int r = blockIdx.x * 4 + wave;
    if (r >= N_NODES) return;
    const int start = row_ptr[r];
    const int end   = row_ptr[r + 1];
    const int lm    = lane & 15;
    float a0 = 0.f, a1 = 0.f, a2 = 0.f, a3 = 0.f;
    int e = start;
    for (; e + 16 <= end; e += 16) {
        const uint2 ed = epack[e + lm];
        #pragma unroll
        for (int k = 0; k < 16; ++k) {
            const int   c = __shfl((int)ed.x, k, 64);
            const float v = __shfl(__uint_as_float(ed.y), k, 64);
            const float h = H[(size_t)c * D + lane];
            if ((k & 3) == 0) a0 = fmaf(v, h, a0);
            else if ((k & 3) == 1) a1 = fmaf(v, h, a1);
            else if ((k & 3) == 2) a2 = fmaf(v, h, a2);
            else a3 = fmaf(v, h, a3);
        }
    }
    const int rem = end - e;
    if (rem > 0) {
        const uint2 ed = (lm < rem) ? epack[e + lm] : make_uint2(0u, 0u);
        for (int k = 0; k < rem; ++k) {
            const int   c = __shfl((int)ed.x, k, 64);
            const float v = __shfl(__uint_as_float(ed.y), k, 64);
            a0 = fmaf(v, H[(size_t)c * D + lane], a0);
        }
    }
    const float acc = (a0 + a1) + (a2 + a3);
    const long long base = (long long)r * D;
    const float sup = (1.0f - alpha) * acc + alpha * H0[base + lane];
    float dot = 0.0f;
    #pragma unroll
    for (int k = 0; k < D; ++k)
        dot = fmaf(__shfl(sup, k, 64), Wlds[k * D + lane], dot);
    out[base + lane] = (1.0f - beta) * sup + beta * dot;
}

// ===========================================================================
// Tier C fallback: f32 atomic scatter + separate epilogue
// ===========================================================================
__global__ void spmm_atomic_kernel(const int* __restrict__ row,
                                   const int* __restrict__ col,
                                   const float* __restrict__ vals,
                                   const float* __restrict__ H,
                                   float* __restrict__ AH) {
    const long long total = (long long)N_EDGES * 16;
    long long idx = (long long)blockIdx.x * blockDim.x + threadIdx.x;
    if (idx >= total) return;
    const int e   = (int)(idx >> 4);
    const int sub = (int)(idx & 15);
    const int r   = row[e];
    const int c   = col[e];
    const float v = vals[e];
    const float4 h = *reinterpret_cast<const float4*>(&H[(long long)c * D + sub * 4]);
    float* dst = &AH[(long long)r * D + sub * 4];
    atomicAdd(dst + 0, v * h.x);
    atomicAdd(dst + 1, v * h.y);
    atomicAdd(dst + 2, v * h.z);
    atomicAdd(dst + 3, v * h.w);
}

__global__ void __launch_bounds__(256)
gcnii_epilogue_kernel(float* __restrict__ AH_out,
                      const float* __restrict__ H0,
                      const float* __restrict__ W,
                      const float* __restrict__ lamda_p,
                      const float* __restrict__ alpha_p,
                      const int* __restrict__ l_p) {
    __shared__ float Wlds[D * D];
    for (int i = threadIdx.x; i < D * D; i += 256) Wlds[i] = W[i];
    __syncthreads();
    const float alpha = alpha_p[0];
    const float beta  = logf(lamda_p[0] / (float)l_p[0] + 1.0f);
    const int wave = threadIdx.x >> 6;
    const int lane = threadIdx.x & 63;
    const int r = blockIdx.x * 4 + wave;
    if (r >= N_NODES) return;
    const long long base = (long long)r * D;
    const float sup = (1.0f - alpha) * AH_out[base + lane] + alpha * H0[base + lane];
    float acc = 0.0f;
    #pragma unroll
    for (int k = 0; k < D; ++k)
        acc = fmaf(__shfl(sup, k, 64), Wlds[k * D + lane], acc);
    AH_out[base + lane] = (1.0f - beta) * sup + beta * acc;
}

// ===========================================================================
extern "C" void kernel_launch(void* const* d_in, const int* in_sizes, int n_in,
                              void* d_out, int out_size, void* d_ws, size_t ws_size,
                              hipStream_t stream) {
    const int*   row   = (const int*)  d_in[0];
    const int*   col   = (const int*)  d_in[1];
    const float* vals  = (const float*)d_in[2];
    const float* H     = (const float*)d_in[3];
    const float* H0    = (const float*)d_in[4];
    const float* W     = (const float*)d_in[5];
    const float* lamda = (const float*)d_in[6];
    const float* alpha = (const float*)d_in[7];
    const int*   l     = (const int*)  d_in[8];
    float* out = (float*)d_out;

    // Tier A layout (4B words):
    //   counts/cursor : [0, 100000)
    //   row_ptr       : [100000, 200001)  (pad to 200064)
    //   totals        : [200064, 200192)
    //   pack          : [200192, 1800256)   (1.6M + 64 pad)
    //   Hh (fp16)     : [1800256, 5000256)
    const size_t neededA = (size_t)5000256 * 4;
    const size_t neededB = (size_t)3500192 * 4;

    if (ws_size >= neededA) {
        int*            counts  = (int*)d_ws;          // doubles as cursor
        int*            row_ptr = counts + 100000;
        int*            totals  = counts + 200064;
        unsigned*       pack    = (unsigned*)(counts + 200192);
        unsigned short* Hh      = (unsigned short*)(counts + 1800256);

        h2half_kernel<<<(N_NODES * D / 4 + 255) / 256, 256, 0, stream>>>(H, Hh);
        hipMemsetAsync(counts, 0, (size_t)N_NODES * sizeof(int), stream);
        hist_kernel<<<(N_EDGES + 255) / 256, 256, 0, stream>>>(row, counts);
        scan1_kernel<<<NCHUNK, 256, 0, stream>>>(counts, row_ptr, totals);
        scan2_kernel<<<NCHUNK, 256, 0, stream>>>(row_ptr, counts, totals);
        scatter_pack_kernel<<<(N_EDGES + 255) / 256, 256, 0, stream>>>(row, col, vals,
                                                                       counts, pack);
        gather_gemm_kernel<<<(N_NODES + 63) / 64, 256, 0, stream>>>(
            row_ptr, pack, Hh, H0, W, lamda, alpha, l, out);
    } else if (ws_size >= neededB) {
        int*   counts  = (int*)d_ws;
        int*   row_ptr = counts + 100000;
        int*   cursor  = counts + 200064;
        int*   totals  = counts + 300064;
        uint2* epack   = (uint2*)(counts + 300192);

        hipMemsetAsync(counts, 0, (size_t)N_NODES * sizeof(int), stream);
        hist_kernel<<<(N_EDGES + 255) / 256, 256, 0, stream>>>(row, counts);
        scan1_kernel<<<NCHUNK, 256, 0, stream>>>(counts, row_ptr, totals);
        scan2_kernel<<<NCHUNK, 256, 0, stream>>>(row_ptr, cursor, totals);
        scatter_kernel<<<(N_EDGES + 255) / 256, 256, 0, stream>>>(row, col, vals,
                                                                  cursor, epack);
        gather_fused_kernel<<<(N_NODES + 3) / 4, 256, 0, stream>>>(
            row_ptr, epack, H, H0, W, lamda, alpha, l, out);
    } else {
        hipMemsetAsync(out, 0, (size_t)out_size * sizeof(float), stream);
        const long long total = (long long)N_EDGES * 16;
        spmm_atomic_kernel<<<(int)((total + 255) / 256), 256, 0, stream>>>(row, col, vals, H, out);
        gcnii_epilogue_kernel<<<(N_NODES + 3) / 4, 256, 0, stream>>>(out, H0, W,
                                                                     lamda, alpha, l);
    }
}

// Round 7
// 143.436 us; speedup vs baseline: 2.5644x; 1.9272x over previous
//
#include <hip/hip_runtime.h>
#include <hip/hip_bf16.h>
#include <hip/hip_fp16.h>

#define N_NODES 100000
#define N_EDGES 1600000
#define D 64
#define CHUNK 1024
#define NCHUNK ((N_NODES + CHUNK - 1) / CHUNK)   // 98

// ---- tier A2 multisplit parameters ----
#define NBIN 200          // bins of 500 rows
#define RPB  500          // rows per bin
#define MS_TILE 4096      // edges per multisplit block
#define MS_CAP  48        // LDS slots per bin per tile (mean 20.5)
#define SCAP 8704         // bin staging cap in bin_sort (mean 8000, +8 sigma)

// ===========================================================================
// Tier A2 build: LDS-buffered two-level counting sort
// ===========================================================================

// --- A2.1: 200-bin histogram (LDS-staged) ----------------------------------
__global__ void __launch_bounds__(256)
bin_hist_kernel(const int* __restrict__ row, int* __restrict__ binCounts) {
    __shared__ int h[NBIN];
    if (threadIdx.x < NBIN) h[threadIdx.x] = 0;
    __syncthreads();
    for (int e = blockIdx.x * blockDim.x + threadIdx.x; e < N_EDGES;
         e += gridDim.x * blockDim.x)
        atomicAdd(&h[row[e] / RPB], 1);
    __syncthreads();
    if (threadIdx.x < NBIN) atomicAdd(&binCounts[threadIdx.x], h[threadIdx.x]);
}

// --- A2.2: scan 200 bin counts -> binBase[0..NBIN], binCursor --------------
__global__ void __launch_bounds__(256)
bin_scan_kernel(const int* __restrict__ binCounts,
                int* __restrict__ binBase, int* __restrict__ binCursor) {
    __shared__ int s[256];
    const int tid = threadIdx.x;
    const int cnt = (tid < NBIN) ? binCounts[tid] : 0;
    s[tid] = cnt;
    __syncthreads();
    for (int off = 1; off < 256; off <<= 1) {
        int t = (tid >= off) ? s[tid - off] : 0;
        __syncthreads();
        s[tid] += t;
        __syncthreads();
    }
    const int excl = s[tid] - cnt;
    if (tid < NBIN) {
        binBase[tid]   = excl;
        binCursor[tid] = excl;
        if (tid == NBIN - 1) binBase[NBIN] = s[tid];   // == N_EDGES
    }
}

// --- A2.3: multisplit — partition edges into 200 bins, LDS-buffered --------
// One tile of 4096 edges per block. Staged (pack,rowlocal) per bin, flushed
// as contiguous runs with ONE cursor atomic per bin per tile.
__global__ void __launch_bounds__(256)
multisplit_kernel(const int* __restrict__ row, const int* __restrict__ col,
                  const float* __restrict__ vals,
                  int* __restrict__ binCursor,
                  unsigned* __restrict__ tmp4, unsigned short* __restrict__ tmp2) {
    __shared__ unsigned       spay[NBIN][MS_CAP];   // 38.4 KB
    __shared__ unsigned short srow[NBIN][MS_CAP];   // 19.2 KB
    __shared__ int bcnt[NBIN];
    __shared__ int gb[NBIN];

    const int tid = threadIdx.x;
    if (tid < NBIN) bcnt[tid] = 0;
    __syncthreads();

    const int base = blockIdx.x * MS_TILE;
    const int eEnd = min(base + MS_TILE, N_EDGES);

    #pragma unroll
    for (int j = 0; j < MS_TILE / 256; ++j) {
        const int e = base + j * 256 + tid;
        if (e < eEnd) {
            const int r = row[e];
            const int c = col[e];
            __half hv = __float2half_rn(vals[e]);       // vals >= 0 -> sign 0
            unsigned short hb;
            __builtin_memcpy(&hb, &hv, 2);
            const unsigned pk = ((unsigned)c << 15) | (hb & 0x7FFFu);
            const int bin = r / RPB;
            const unsigned short rl = (unsigned short)(r - bin * RPB);
            const int p = atomicAdd(&bcnt[bin], 1);
            if (p < MS_CAP) {
                spay[bin][p] = pk;
                srow[bin][p] = rl;
            } else {                                    // rare spill
                const int g = atomicAdd(&binCursor[bin], 1);
                tmp4[g] = pk;
                tmp2[g] = rl;
            }
        }
    }
    __syncthreads();

    if (tid < NBIN) {
        const int c = min(bcnt[tid], MS_CAP);
        gb[tid] = atomicAdd(&binCursor[tid], c);
    }
    __syncthreads();

    for (int i = tid; i < NBIN * MS_CAP; i += 256) {
        const int bin  = i / MS_CAP;
        const int slot = i - bin * MS_CAP;
        if (slot < min(bcnt[bin], MS_CAP)) {
            const int g = gb[bin] + slot;
            tmp4[g] = spay[bin][slot];
            tmp2[g] = srow[bin][slot];
        }
    }
}

// --- A2.4: per-bin LDS counting sort -> row_ptr + sorted pack --------------
// One block (512 thr) per bin. All random writes confined to LDS / one L2.
__global__ void __launch_bounds__(512)
bin_sort_kernel(const int* __restrict__ binBase,
                const unsigned* __restrict__ tmp4, const unsigned short* __restrict__ tmp2,
                int* __restrict__ row_ptr, unsigned* __restrict__ pack) {
    __shared__ unsigned       pay[SCAP];     // 34.8 KB
    __shared__ unsigned short rl[SCAP];      // 17.4 KB
    __shared__ int rcnt[512];                // counts -> cursors
    __shared__ int rex[512];                 // scan buffer

    const int tid = threadIdx.x;
    const int b    = blockIdx.x;
    const int base = binBase[b];
    const int nb   = binBase[b + 1] - base;
    const int row0 = b * RPB;

    if (tid < 512) rcnt[tid] = 0;
    __syncthreads();

    // phase A: stage + histogram
    for (int i = tid; i < nb; i += 512) {
        const unsigned       p = tmp4[base + i];
        const unsigned short r = tmp2[base + i];
        if (i < SCAP) { pay[i] = p; rl[i] = r; }
        atomicAdd(&rcnt[r], 1);
    }
    __syncthreads();

    // phase B: exclusive scan of 500 counts (Hillis-Steele over 512)
    const int cnt = rcnt[tid];
    rex[tid] = cnt;
    __syncthreads();
    for (int off = 1; off < 512; off <<= 1) {
        int t = (tid >= off) ? rex[tid - off] : 0;
        __syncthreads();
        rex[tid] += t;
        __syncthreads();
    }
    const int excl = rex[tid] - cnt;
    if (tid < RPB) row_ptr[row0 + tid] = base + excl;
    if (b == NBIN - 1 && tid == 0) row_ptr[N_NODES] = N_EDGES;
    __syncthreads();
    rcnt[tid] = excl;          // reuse as within-bin cursor
    __syncthreads();

    // phase C: scatter into sorted order (writes span ~64KB -> L2-combined)
    for (int i = tid; i < nb; i += 512) {
        unsigned p; unsigned short r;
        if (i < SCAP) { p = pay[i]; r = rl[i]; }
        else          { p = tmp4[base + i]; r = tmp2[base + i]; }
        const int d = atomicAdd(&rcnt[r], 1);
        pack[base + d] = p;
    }
}

// ===========================================================================
// Shared: H -> fp16
// ===========================================================================
__global__ void __launch_bounds__(256)
h2half_kernel(const float* __restrict__ H, unsigned short* __restrict__ Hh) {
    const int tid = blockIdx.x * blockDim.x + threadIdx.x;
    const int total = N_NODES * D / 4;
    if (tid >= total) return;
    const float4 f = reinterpret_cast<const float4*>(H)[tid];
    __half2 h01 = __floats2half2_rn(f.x, f.y);
    __half2 h23 = __floats2half2_rn(f.z, f.w);
    uint2 u;
    __builtin_memcpy(&u.x, &h01, 4);
    __builtin_memcpy(&u.y, &h23, 4);
    reinterpret_cast<uint2*>(Hh)[tid] = u;
}

// ===========================================================================
// Fused gather-SPMM + GCNII epilogue (round-6 proven)
// ===========================================================================
__device__ inline float h_from_bits(unsigned bits) {
    unsigned short us = (unsigned short)bits;
    __half h;
    __builtin_memcpy(&h, &us, 2);
    return __half2float(h);
}

__global__ void __launch_bounds__(256)
gather_gemm_kernel(const int* __restrict__ row_ptr,
                   const unsigned* __restrict__ pack,
                   const unsigned short* __restrict__ Hh,
                   const float* __restrict__ H0,
                   const float* __restrict__ W,
                   const float* __restrict__ lamda_p, const float* __restrict__ alpha_p,
                   const int* __restrict__ l_p,
                   float* __restrict__ out) {
    __shared__ float supT[D][68];
    __shared__ float Wl[D][D];

    const int tid = threadIdx.x;
    for (int i = tid; i < D * D; i += 256) ((float*)Wl)[i] = W[i];

    const float alpha = alpha_p[0];
    const float beta  = logf(lamda_p[0] / (float)l_p[0] + 1.0f);

    const int wave = tid >> 6;
    const int lane = tid & 63;
    const int R0 = blockIdx.x * 64;
    const int rbase = R0 + wave * 16;

    int rpidx = rbase + ((lane < 17) ? lane : 16);
    if (rpidx > N_NODES) rpidx = N_NODES;
    const int rp_l = row_ptr[rpidx];

    for (int i = 0; i < 16; ++i) {
        const int r = rbase + i;
        if (r >= N_NODES) break;
        const int s = __builtin_amdgcn_readlane(rp_l, i);
        const int t = __builtin_amdgcn_readlane(rp_l, i + 1);

        float a0 = 0.f, a1 = 0.f, a2 = 0.f, a3 = 0.f;
        for (int e = s; e < t; e += 16) {
            int ei = e + (lane & 15);
            if (ei > t - 1) ei = t - 1;
            const unsigned p_l = pack[ei];
            #pragma unroll
            for (int k = 0; k < 16; ++k) {
                const unsigned p = (unsigned)__builtin_amdgcn_readlane((int)p_l, k);
                const unsigned vbits = (e + k < t) ? (p & 0x7FFFu) : 0u;
                const float v = h_from_bits(vbits);
                const unsigned short hb = Hh[(size_t)(p >> 15) * D + lane];
                __half hh; __builtin_memcpy(&hh, &hb, 2);
                const float hf = __half2float(hh);
                if ((k & 3) == 0) a0 = fmaf(v, hf, a0);
                else if ((k & 3) == 1) a1 = fmaf(v, hf, a1);
                else if ((k & 3) == 2) a2 = fmaf(v, hf, a2);
                else a3 = fmaf(v, hf, a3);
            }
        }
        const float acc = (a0 + a1) + (a2 + a3);
        const float sup = (1.0f - alpha) * acc + alpha * H0[(size_t)r * D + lane];
        supT[lane][wave * 16 + i] = sup;
    }
    __syncthreads();

    const int ty = tid >> 4;
    const int tx = tid & 15;
    float acc[4][4] = {{0.f}};

    #pragma unroll 8
    for (int k = 0; k < D; ++k) {
        const float4 A = *reinterpret_cast<const float4*>(&supT[k][4 * ty]);
        const float4 B = *reinterpret_cast<const float4*>(&Wl[k][4 * tx]);
        acc[0][0] = fmaf(A.x, B.x, acc[0][0]); acc[0][1] = fmaf(A.x, B.y, acc[0][1]);
        acc[0][2] = fmaf(A.x, B.z, acc[0][2]); acc[0][3] = fmaf(A.x, B.w, acc[0][3]);
        acc[1][0] = fmaf(A.y, B.x, acc[1][0]); acc[1][1] = fmaf(A.y, B.y, acc[1][1]);
        acc[1][2] = fmaf(A.y, B.z, acc[1][2]); acc[1][3] = fmaf(A.y, B.w, acc[1][3]);
        acc[2][0] = fmaf(A.z, B.x, acc[2][0]); acc[2][1] = fmaf(A.z, B.y, acc[2][1]);
        acc[2][2] = fmaf(A.z, B.z, acc[2][2]); acc[2][3] = fmaf(A.z, B.w, acc[2][3]);
        acc[3][0] = fmaf(A.w, B.x, acc[3][0]); acc[3][1] = fmaf(A.w, B.y, acc[3][1]);
        acc[3][2] = fmaf(A.w, B.z, acc[3][2]); acc[3][3] = fmaf(A.w, B.w, acc[3][3]);
    }

    #pragma unroll
    for (int i = 0; i < 4; ++i) {
        const int r = R0 + 4 * ty + i;
        if (r < N_NODES) {
            float4 o;
            o.x = (1.0f - beta) * supT[4 * tx + 0][4 * ty + i] + beta * acc[i][0];
            o.y = (1.0f - beta) * supT[4 * tx + 1][4 * ty + i] + beta * acc[i][1];
            o.z = (1.0f - beta) * supT[4 * tx + 2][4 * ty + i] + beta * acc[i][2];
            o.w = (1.0f - beta) * supT[4 * tx + 3][4 * ty + i] + beta * acc[i][3];
            *reinterpret_cast<float4*>(&out[(size_t)r * D + 4 * tx]) = o;
        }
    }
}

// ===========================================================================
// Tier A fallback build (round-6): hist + scan + atomic-cursor scatter
// ===========================================================================
__global__ void hist_kernel(const int* __restrict__ row, int* __restrict__ counts) {
    int e = blockIdx.x * blockDim.x + threadIdx.x;
    if (e >= N_EDGES) return;
    atomicAdd(&counts[row[e]], 1);
}

__global__ void __launch_bounds__(256)
scan1_kernel(const int* __restrict__ counts, int* __restrict__ row_ptr,
             int* __restrict__ chunkTotals) {
    __shared__ int s[256];
    const int t = threadIdx.x;
    const int base = blockIdx.x * CHUNK + t * 4;
    int c0 = (base + 0 < N_NODES) ? counts[base + 0] : 0;
    int c1 = (base + 1 < N_NODES) ? counts[base + 1] : 0;
    int c2 = (base + 2 < N_NODES) ? counts[base + 2] : 0;
    int c3 = (base + 3 < N_NODES) ? counts[base + 3] : 0;
    const int sum = c0 + c1 + c2 + c3;
    s[t] = sum;
    __syncthreads();
    for (int off = 1; off < 256; off <<= 1) {
        int u = (t >= off) ? s[t - off] : 0;
        __syncthreads();
        s[t] += u;
        __syncthreads();
    }
    const int excl = s[t] - sum;
    if (base + 0 < N_NODES) row_ptr[base + 0] = excl;
    if (base + 1 < N_NODES) row_ptr[base + 1] = excl + c0;
    if (base + 2 < N_NODES) row_ptr[base + 2] = excl + c0 + c1;
    if (base + 3 < N_NODES) row_ptr[base + 3] = excl + c0 + c1 + c2;
    if (t == 255) chunkTotals[blockIdx.x] = s[255];
}

__global__ void __launch_bounds__(256)
scan2_kernel(int* __restrict__ row_ptr, int* __restrict__ cursor,
             const int* __restrict__ chunkTotals) {
    int offset = 0;
    for (int i = 0; i < (int)blockIdx.x; ++i) offset += chunkTotals[i];
    const int idx = blockIdx.x * CHUNK + threadIdx.x * 4;
    #pragma unroll
    for (int j = 0; j < 4; ++j) {
        const int k = idx + j;
        if (k < N_NODES) {
            const int v = row_ptr[k] + offset;
            row_ptr[k] = v;
            cursor[k]  = v;
        }
    }
    if (blockIdx.x == 0 && threadIdx.x == 0) row_ptr[N_NODES] = N_EDGES;
}

__global__ void scatter_pack_kernel(const int* __restrict__ row, const int* __restrict__ col,
                                    const float* __restrict__ vals,
                                    int* __restrict__ cursor,
                                    unsigned* __restrict__ pack) {
    int e = blockIdx.x * blockDim.x + threadIdx.x;
    if (e >= N_EDGES) return;
    const int pos = atomicAdd(&cursor[row[e]], 1);
    __half hv = __float2half_rn(vals[e]);
    unsigned short hb;
    __builtin_memcpy(&hb, &hv, 2);
    pack[pos] = ((unsigned)col[e] << 15) | (hb & 0x7FFFu);
}

// ===========================================================================
// Tier C fallback: f32 atomic scatter + separate epilogue
// ===========================================================================
__global__ void spmm_atomic_kernel(const int* __restrict__ row,
                                   const int* __restrict__ col,
                                   const float* __restrict__ vals,
                                   const float* __restrict__ H,
                                   float* __restrict__ AH) {
    const long long total = (long long)N_EDGES * 16;
    long long idx = (long long)blockIdx.x * blockDim.x + threadIdx.x;
    if (idx >= total) return;
    const int e   = (int)(idx >> 4);
    const int sub = (int)(idx & 15);
    const int r   = row[e];
    const int c   = col[e];
    const float v = vals[e];
    const float4 h = *reinterpret_cast<const float4*>(&H[(long long)c * D + sub * 4]);
    float* dst = &AH[(long long)r * D + sub * 4];
    atomicAdd(dst + 0, v * h.x);
    atomicAdd(dst + 1, v * h.y);
    atomicAdd(dst + 2, v * h.z);
    atomicAdd(dst + 3, v * h.w);
}

__global__ void __launch_bounds__(256)
gcnii_epilogue_kernel(float* __restrict__ AH_out,
                      const float* __restrict__ H0,
                      const float* __restrict__ W,
                      const float* __restrict__ lamda_p,
                      const float* __restrict__ alpha_p,
                      const int* __restrict__ l_p) {
    __shared__ float Wlds[D * D];
    for (int i = threadIdx.x; i < D * D; i += 256) Wlds[i] = W[i];
    __syncthreads();
    const float alpha = alpha_p[0];
    const float beta  = logf(lamda_p[0] / (float)l_p[0] + 1.0f);
    const int wave = threadIdx.x >> 6;
    const int lane = threadIdx.x & 63;
    const int r = blockIdx.x * 4 + wave;
    if (r >= N_NODES) return;
    const long long base = (long long)r * D;
    const float sup = (1.0f - alpha) * AH_out[base + lane] + alpha * H0[base + lane];
    float acc = 0.0f;
    #pragma unroll
    for (int k = 0; k < D; ++k)
        acc = fmaf(__shfl(sup, k, 64), Wlds[k * D + lane], acc);
    AH_out[base + lane] = (1.0f - beta) * sup + beta * acc;
}

// ===========================================================================
extern "C" void kernel_launch(void* const* d_in, const int* in_sizes, int n_in,
                              void* d_out, int out_size, void* d_ws, size_t ws_size,
                              hipStream_t stream) {
    const int*   row   = (const int*)  d_in[0];
    const int*   col   = (const int*)  d_in[1];
    const float* vals  = (const float*)d_in[2];
    const float* H     = (const float*)d_in[3];
    const float* H0    = (const float*)d_in[4];
    const float* W     = (const float*)d_in[5];
    const float* lamda = (const float*)d_in[6];
    const float* alpha = (const float*)d_in[7];
    const int*   l     = (const int*)  d_in[8];
    float* out = (float*)d_out;

    // Tier A2 layout (4B words):
    //   binCounts : [0, 256)
    //   binBase   : [256, 512)       (201 used)
    //   binCursor : [512, 768)
    //   row_ptr   : [768, 100800)    (100001 used)
    //   pack4     : [100800, 1700800)
    //   tmp2(u16) : [1700800, 2500800)
    //   tmp4      : [2500800, 4100800)
    //   Hh (fp16) : [4100800, 7300800)
    const size_t neededA2 = (size_t)7300800 * 4;   // 29.2 MB
    const size_t neededA  = (size_t)5000256 * 4;   // 20.0 MB (round-6 path)
    const size_t neededC  = 0;

    if (ws_size >= neededA2) {
        int*            binCounts = (int*)d_ws;
        int*            binBase   = binCounts + 256;
        int*            binCursor = binCounts + 512;
        int*            row_ptr   = binCounts + 768;
        unsigned*       pack      = (unsigned*)(binCounts + 100800);
        unsigned short* tmp2      = (unsigned short*)(binCounts + 1700800);
        unsigned*       tmp4      = (unsigned*)(binCounts + 2500800);
        unsigned short* Hh        = (unsigned short*)(binCounts + 4100800);

        h2half_kernel<<<(N_NODES * D / 4 + 255) / 256, 256, 0, stream>>>(H, Hh);
        hipMemsetAsync(binCounts, 0, NBIN * sizeof(int), stream);
        bin_hist_kernel<<<256, 256, 0, stream>>>(row, binCounts);
        bin_scan_kernel<<<1, 256, 0, stream>>>(binCounts, binBase, binCursor);
        multisplit_kernel<<<(N_EDGES + MS_TILE - 1) / MS_TILE, 256, 0, stream>>>(
            row, col, vals, binCursor, tmp4, tmp2);
        bin_sort_kernel<<<NBIN, 512, 0, stream>>>(binBase, tmp4, tmp2, row_ptr, pack);
        gather_gemm_kernel<<<(N_NODES + 63) / 64, 256, 0, stream>>>(
            row_ptr, pack, Hh, H0, W, lamda, alpha, l, out);
    } else if (ws_size >= neededA) {
        // round-6 tier A
        int*            counts  = (int*)d_ws;
        int*            row_ptr = counts + 100000;
        int*            totals  = counts + 200064;
        unsigned*       pack    = (unsigned*)(counts + 200192);
        unsigned short* Hh      = (unsigned short*)(counts + 1800256);

        h2half_kernel<<<(N_NODES * D / 4 + 255) / 256, 256, 0, stream>>>(H, Hh);
        hipMemsetAsync(counts, 0, (size_t)N_NODES * sizeof(int), stream);
        hist_kernel<<<(N_EDGES + 255) / 256, 256, 0, stream>>>(row, counts);
        scan1_kernel<<<NCHUNK, 256, 0, stream>>>(counts, row_ptr, totals);
        scan2_kernel<<<NCHUNK, 256, 0, stream>>>(row_ptr, counts, totals);
        scatter_pack_kernel<<<(N_EDGES + 255) / 256, 256, 0, stream>>>(row, col, vals,
                                                                       counts, pack);
        gather_gemm_kernel<<<(N_NODES + 63) / 64, 256, 0, stream>>>(
            row_ptr, pack, Hh, H0, W, lamda, alpha, l, out);
    } else {
        hipMemsetAsync(out, 0, (size_t)out_size * sizeof(float), stream);
        const long long total = (long long)N_EDGES * 16;
        spmm_atomic_kernel<<<(int)((total + 255) / 256), 256, 0, stream>>>(row, col, vals, H, out);
        gcnii_epilogue_kernel<<<(N_NODES + 3) / 4, 256, 0, stream>>>(out, H0, W,
                                                                     lamda, alpha, l);
    }
}